// Round 12
// baseline (232.073 us; speedup 1.0000x reference)
//
#include <hip/hip_runtime.h>

#define B_ROWS 8192
#define FEAT   256
#define NCH    8           // j-range chunks: ch = bid&7 -> 8 x 64 = 512 blocks
#define CH_COLS 1024
#define NJT    16          // 64-col j-tiles per chunk
#define NBLK   512
#define MAGIC  0x1357ACE5u

typedef float f32x4 __attribute__((ext_vector_type(4)));
typedef _Float16 f16x8 __attribute__((ext_vector_type(8)));

typedef const __attribute__((address_space(1))) unsigned int* gas_ptr;
typedef __attribute__((address_space(3))) unsigned int* las_ptr;

__device__ __forceinline__ void gload_lds16(const void* g, void* l) {
  // HW semantics: LDS dest = wave-uniform base + lane*16
  __builtin_amdgcn_global_load_lds((gas_ptr)g, (las_ptr)l, 16, 0, 0);
}

// device-scope grid barrier: monotonic count to NBLK (no reset; one counter
// per barrier instance, zeroed by block 0 each launch -> graph-replay safe)
__device__ __forceinline__ void grid_barrier(unsigned* cnt) {
  __syncthreads();
  if (threadIdx.x == 0) {
    __threadfence();                                   // release my writes
    atomicAdd(cnt, 1u);
    while (__hip_atomic_load(cnt, __ATOMIC_ACQUIRE,
                             __HIP_MEMORY_SCOPE_AGENT) < NBLK)
      __builtin_amdgcn_s_sleep(1);
  }
  __syncthreads();                                     // broadcast arrival
}

// ---- single fused persistent kernel: prep -> barrier -> gram+snn ->
//      barrier -> final.  512 blocks x 256 thr = exactly 2 blocks/CU.
__global__ __launch_bounds__(256, 2) void snn_fused(
    const float* __restrict__ x, const int* __restrict__ y,
    const float* __restrict__ T,
    unsigned* __restrict__ bar,            // [0],[1]=barriers, [2]=init flag
    float* __restrict__ part_s, float* __restrict__ part_q,
    float* __restrict__ sq, unsigned short* __restrict__ xh,
    float* __restrict__ pden, float* __restrict__ pnum,
    float* __restrict__ out)
{
  __shared__ __align__(16) char lB[32768];
  int tid = threadIdx.x;
  int l = tid & 63, wid = tid >> 6;
  int quad = l >> 4, l15 = l & 15;
  int l5 = l >> 5, s31 = l & 31;
  int bid = blockIdx.x;
  int ch = bid & 7, it = bid >> 3;
  int i0 = it * 128, chbase = ch * CH_COLS;

  // ---- barrier init (ws is 0xAA-poisoned each call; block 0 re-inits)
  if (bid == 0 && tid == 0) {
    bar[0] = 0u; bar[1] = 0u;
    __threadfence();
    __hip_atomic_store(&bar[2], MAGIC, __ATOMIC_RELEASE,
                       __HIP_MEMORY_SCOPE_AGENT);
  }
  if (tid == 0) {
    while (__hip_atomic_load(&bar[2], __ATOMIC_ACQUIRE,
                             __HIP_MEMORY_SCOPE_AGENT) != MAGIC)
      __builtin_amdgcn_s_sleep(1);
  }
  __syncthreads();

  // ---- phase 1: fp16 convert + row ssq + block partial sums (16 rows/blk)
  {
    float ls = 0.f, lq = 0.f;
    #pragma unroll
    for (int p = 0; p < 4; ++p) {
      int row = bid*16 + p*4 + wid;
      float4 v = ((const float4*)(x + (size_t)row * FEAT))[l];
      ushort4 u;
      u.x = __builtin_bit_cast(unsigned short, (_Float16)v.x);
      u.y = __builtin_bit_cast(unsigned short, (_Float16)v.y);
      u.z = __builtin_bit_cast(unsigned short, (_Float16)v.z);
      u.w = __builtin_bit_cast(unsigned short, (_Float16)v.w);
      ((ushort4*)(xh + (size_t)row * FEAT))[l] = u;
      float q = v.x*v.x + v.y*v.y + v.z*v.z + v.w*v.w;
      ls += v.x + v.y + v.z + v.w;
      lq += q;
      float rq = q;
      #pragma unroll
      for (int m = 32; m; m >>= 1) rq += __shfl_xor(rq, m);
      if (l == 0) sq[row] = rq;
    }
    #pragma unroll
    for (int m = 32; m; m >>= 1) {
      ls += __shfl_xor(ls, m);
      lq += __shfl_xor(lq, m);
    }
    __shared__ float red[8];
    if (l == 0) { red[wid] = ls; red[4 + wid] = lq; }
    __syncthreads();
    if (tid == 0) {
      part_s[bid] = red[0]+red[1]+red[2]+red[3];
      part_q[bid] = red[4]+red[5]+red[6]+red[7];
    }
  }

  grid_barrier(&bar[0]);   // xh, sq, partials visible everywhere

  // ---- phase 2: fused Gram GEMM + SNN accumulation (R11 body)
  {
    const char* xbc = (const char*)xh;

    // A fragments -> registers (MFMA layout, straight from global/L2)
    f16x8 areg[2][8];
    #pragma unroll
    for (int rb = 0; rb < 2; ++rb)
      #pragma unroll
      for (int kk = 0; kk < 8; ++kk)
        areg[rb][kk] = *(const f16x8*)(xbc +
            (size_t)(i0 + wid*32 + rb*16 + l15)*512 + kk*64 + quad*16);

    // uniform scale from the 512 partials (per-wave redundant)
    float s_acc = 0.f, q_acc = 0.f;
    #pragma unroll
    for (int t = 0; t < 8; ++t) {
      s_acc += part_s[l + 64*t];
      q_acc += part_q[l + 64*t];
    }
    #pragma unroll
    for (int m = 1; m <= 32; m <<= 1) {
      s_acc += __shfl_xor(s_acc, m);
      q_acc += __shfl_xor(q_acc, m);
    }
    const double n = (double)B_ROWS * FEAT;
    double var = ((double)q_acc - (double)s_acc*(double)s_acc/n) / (n - 1.0);
    float stdv = (float)sqrt(var);
    float p10  = __builtin_amdgcn_exp2f(T[0] * 3.3219280948873623f);
    float nscale2 = -(p10 * 1.4426950408889634f / stdv);

    float sqi[8]; int yiv[8];
    int i0q = i0 + wid*32 + quad*4;
    #pragma unroll
    for (int rb = 0; rb < 2; ++rb)
      #pragma unroll
      for (int r = 0; r < 4; ++r) {
        int idx = i0q + rb*16 + r;
        sqi[rb*4+r] = sq[idx];
        yiv[rb*4+r] = y[idx];
      }

    float sden[8], snum[8];
    #pragma unroll
    for (int v = 0; v < 8; ++v) { sden[v] = 0.f; snum[v] = 0.f; }
    f32x4 acc[2][4];
    const f32x4 zero4 = {0.f, 0.f, 0.f, 0.f};

    for (int jt = 0; jt < NJT; ++jt) {
      int j0 = chbase + jt * 64;

      __syncthreads();   // all waves done reading lB of previous tile
      {
        const char* gB = xbc + (size_t)j0 * 512;
        #pragma unroll
        for (int s = 0; s < 8; ++s) {
          int c  = wid*8 + s;
          int rw = 2*c + l5;
          int gg = s31 ^ (rw & 7);
          gload_lds16(gB + rw*512 + gg*16, lB + c*1024);
        }
      }

      if (jt > 0) {
        int pj0 = j0 - 64;
        bool dg = (pj0 == i0 || pj0 == i0 + 64);
        int jb = pj0 + l15;
        float sqj[4]; int yj[4];
        #pragma unroll
        for (int cb = 0; cb < 4; ++cb) {
          int j = jb + cb*16;
          sqj[cb] = sq[j]; yj[cb] = y[j];
        }
        #pragma unroll
        for (int rb = 0; rb < 2; ++rb)
          #pragma unroll
          for (int r = 0; r < 4; ++r) {
            float si = sqi[rb*4+r];
            int   ig = i0q + rb*16 + r;
            int   yi = yiv[rb*4+r];
            float dacc = 0.f, nacc = 0.f;
            #pragma unroll
            for (int cb = 0; cb < 4; ++cb) {
              float S  = acc[rb][cb][r];
              float d2 = fmaxf(fmaf(S, -2.0f, si + sqj[cb]), 0.0f);
              float e  = __builtin_amdgcn_exp2f(
                           __builtin_amdgcn_sqrtf(d2) * nscale2);
              bool offd = !dg || (ig != jb + cb*16);
              dacc += offd ? e : 0.0f;
              nacc += (yi == yj[cb] && offd) ? e : 0.0f;
            }
            sden[rb*4+r] += dacc;
            snum[rb*4+r] += nacc;
          }
      }
      #pragma unroll
      for (int rb = 0; rb < 2; ++rb)
        #pragma unroll
        for (int cb = 0; cb < 4; ++cb)
          acc[rb][cb] = zero4;

      __syncthreads();   // drains vmcnt: B tile visible

      #pragma unroll
      for (int kk = 0; kk < 8; ++kk) {
        f16x8 bv[4];
        #pragma unroll
        for (int cb = 0; cb < 4; ++cb) {
          int nr = cb*16 + l15;
          bv[cb] = *(const f16x8*)(lB + nr*512 +
                     ((((kk<<2)|quad) ^ (l15 & 7)) << 4));
        }
        #pragma unroll
        for (int rb = 0; rb < 2; ++rb)
          #pragma unroll
          for (int cb = 0; cb < 4; ++cb)
            acc[rb][cb] = __builtin_amdgcn_mfma_f32_16x16x32_f16(
                areg[rb][kk], bv[cb], acc[rb][cb], 0, 0, 0);
      }
    }
    // last tile epilogue
    {
      int pj0 = chbase + (NJT-1) * 64;
      bool dg = (pj0 == i0 || pj0 == i0 + 64);
      int jb = pj0 + l15;
      float sqj[4]; int yj[4];
      #pragma unroll
      for (int cb = 0; cb < 4; ++cb) {
        int j = jb + cb*16;
        sqj[cb] = sq[j]; yj[cb] = y[j];
      }
      #pragma unroll
      for (int rb = 0; rb < 2; ++rb)
        #pragma unroll
        for (int r = 0; r < 4; ++r) {
          float si = sqi[rb*4+r];
          int   ig = i0q + rb*16 + r;
          int   yi = yiv[rb*4+r];
          float dacc = 0.f, nacc = 0.f;
          #pragma unroll
          for (int cb = 0; cb < 4; ++cb) {
            float S  = acc[rb][cb][r];
            float d2 = fmaxf(fmaf(S, -2.0f, si + sqj[cb]), 0.0f);
            float e  = __builtin_amdgcn_exp2f(
                         __builtin_amdgcn_sqrtf(d2) * nscale2);
            bool offd = !dg || (ig != jb + cb*16);
            dacc += offd ? e : 0.0f;
            nacc += (yi == yj[cb] && offd) ? e : 0.0f;
          }
          sden[rb*4+r] += dacc;
          snum[rb*4+r] += nacc;
        }
    }

    // reduce across the 16 lanes of each quad, store partials
    #pragma unroll
    for (int v = 0; v < 8; ++v) {
      #pragma unroll
      for (int m = 1; m <= 8; m <<= 1) {
        sden[v] += __shfl_xor(sden[v], m);
        snum[v] += __shfl_xor(snum[v], m);
      }
    }
    if (l15 == 0) {
      int base = (it*NCH + ch) * 128;
      #pragma unroll
      for (int rb = 0; rb < 2; ++rb)
        #pragma unroll
        for (int r = 0; r < 4; ++r) {
          int rin = wid*32 + rb*16 + quad*4 + r;
          pden[base + rin] = sden[rb*4+r];
          pnum[base + rin] = snum[rb*4+r];
        }
    }
  }

  grid_barrier(&bar[1]);   // pden/pnum visible

  // ---- phase 3: final loss on block 0 (proven R8 loop; logf is LOG2!)
  if (bid == 0) {
    float tot = 0.f;
    for (int k = 0; k < 32; ++k) {
      int row = tid + 256*k;
      int itt = row >> 7, rin = row & 127;
      float den = 0.f, num = 0.f;
      #pragma unroll
      for (int p = 0; p < NCH; ++p) {
        den += pden[(itt*NCH + p)*128 + rin];
        num += pnum[(itt*NCH + p)*128 + rin];
      }
      if (num > 0.f)
        tot += 0.6931471805599453f *
               (__builtin_amdgcn_logf(num) - __builtin_amdgcn_logf(den));
    }
    #pragma unroll
    for (int m = 32; m; m >>= 1) tot += __shfl_xor(tot, m);
    __shared__ float fred[4];
    if (l == 0) fred[wid] = tot;
    __syncthreads();
    if (tid == 0)
      out[0] = -(fred[0]+fred[1]+fred[2]+fred[3]) / 8192.0f;
  }
}

extern "C" void kernel_launch(void* const* d_in, const int* in_sizes, int n_in,
                              void* d_out, int out_size, void* d_ws, size_t ws_size,
                              hipStream_t stream)
{
  (void)in_sizes; (void)n_in; (void)out_size; (void)ws_size;
  const float* x  = (const float*)d_in[0];
  const int* y    = (const int*)d_in[1];   // int64 in reference -> int32 here
  const float* T  = (const float*)d_in[2];
  char* ws = (char*)d_ws;
  unsigned* bar = (unsigned*)ws;                         // 12 B (barriers)
  float* part_s = (float*)(ws + 1024);                   // 2 KB
  float* part_q = (float*)(ws + 4096);                   // 2 KB
  float* sq     = (float*)(ws + 32768);                  // 32 KB
  unsigned short* xh = (unsigned short*)(ws + 65536);    // 4 MB fp16
  float* pden   = (float*)(ws + 65536 + 4194304);        // 64*8*128 f32
  float* pnum   = pden + 64*NCH*128;

  hipLaunchKernelGGL(snn_fused, dim3(NBLK), dim3(256), 0, stream,
                     x, y, T, bar, part_s, part_q, sq, xh,
                     pden, pnum, (float*)d_out);
}

// Round 13
// 193.784 us; speedup vs baseline: 1.1976x; 1.1976x over previous
//
#include <hip/hip_runtime.h>

#define B_ROWS 8192
#define FEAT   256
#define NPAIR  2080        // 64*65/2 triangular tile pairs
#define TILE_B 65536       // 128 rows x 512 B (256 fp16)

typedef float f32x4 __attribute__((ext_vector_type(4)));
typedef _Float16 f16x8 __attribute__((ext_vector_type(8)));

// ---- kernel 1: fp16 convert, row ssq, per-block f32 partials;
//      blocks 0..63 also zero gden/gnum (16384 floats)
__global__ __launch_bounds__(256) void prep_kernel(
    const float* __restrict__ x, unsigned short* __restrict__ xh,
    float* __restrict__ sq, float* __restrict__ part_s,
    float* __restrict__ part_q, float* __restrict__ gden)
{
  int tid = threadIdx.x;
  int l = tid & 63, wid = tid >> 6;
  int row = blockIdx.x * 4 + wid;
  if (blockIdx.x < 64) gden[blockIdx.x * 256 + tid] = 0.f;  // gden+gnum contiguous
  const float4* xv = (const float4*)(x + (size_t)row * FEAT);
  float4 v = xv[l];
  ushort4 u;
  u.x = __builtin_bit_cast(unsigned short, (_Float16)v.x);
  u.y = __builtin_bit_cast(unsigned short, (_Float16)v.y);
  u.z = __builtin_bit_cast(unsigned short, (_Float16)v.z);
  u.w = __builtin_bit_cast(unsigned short, (_Float16)v.w);
  ((ushort4*)(xh + (size_t)row * FEAT))[l] = u;
  float ssq  = v.x*v.x + v.y*v.y + v.z*v.z + v.w*v.w;
  float ssum = v.x + v.y + v.z + v.w;
  #pragma unroll
  for (int m = 32; m; m >>= 1) {
    ssq  += __shfl_xor(ssq, m);
    ssum += __shfl_xor(ssum, m);
  }
  if (l == 0) sq[row] = ssq;
  __shared__ float red[8];
  if (l == 0) { red[wid*2] = ssum; red[wid*2+1] = ssq; }
  __syncthreads();
  if (tid == 0) {
    part_s[blockIdx.x] = red[0]+red[2]+red[4]+red[6];
    part_q[blockIdx.x] = red[1]+red[3]+red[5]+red[7];
  }
}

// ---- kernel 2: triangular fused Gram + SNN accumulation (R5 body,
// fingerprint-proven correct; only the scale source changed to partials).
// one block per (ti,tj) pair, tj>=ti; 512 thr = 8 waves, wave tile 32x64.
__global__ __launch_bounds__(512, 2) void snn_main(
    const unsigned short* __restrict__ xh, const float* __restrict__ sq,
    const int* __restrict__ y, const float* __restrict__ T,
    const float* __restrict__ part_s, const float* __restrict__ part_q,
    float* __restrict__ gden, float* __restrict__ gnum)
{
  extern __shared__ char smem[];
  char* lA = smem;
  char* lB = smem + TILE_B;
  int tid = threadIdx.x;
  int l = tid & 63, w = tid >> 6;
  int quad = l >> 4, l15 = l & 15;
  int wr = w >> 1, wc = w & 1;

  // decode triangular pair index
  int p = blockIdx.x;
  int ti = (int)((129.0 - sqrt(129.0*129.0 - 8.0*(double)p)) * 0.5);
  while ((ti+1)*(129-(ti+1))/2 <= p) ++ti;
  while (ti*(129-ti)/2 > p) --ti;
  int tj = ti + (p - ti*(129-ti)/2);
  bool diag = (ti == tj);
  int i0 = ti*128, j0 = tj*128;

  // stage A (and B if off-diagonal): proven register round-trip + swizzle
  const char* xbc = (const char*)xh;
  {
    const uint4* gA = (const uint4*)(xbc + (size_t)i0*512);
    uint4 ta[8], tb[8];
    #pragma unroll
    for (int s = 0; s < 8; ++s) ta[s] = gA[s*512 + tid];
    if (!diag) {
      const uint4* gB = (const uint4*)(xbc + (size_t)j0*512);
      #pragma unroll
      for (int s = 0; s < 8; ++s) tb[s] = gB[s*512 + tid];
    }
    #pragma unroll
    for (int s = 0; s < 8; ++s) {
      int ll = s*512 + tid;
      int rw = ll >> 5, g = ll & 31;
      *(uint4*)(lA + rw*512 + ((g ^ (rw & 7)) << 4)) = ta[s];
    }
    if (!diag) {
      #pragma unroll
      for (int s = 0; s < 8; ++s) {
        int ll = s*512 + tid;
        int rw = ll >> 5, g = ll & 31;
        *(uint4*)(lB + rw*512 + ((g ^ (rw & 7)) << 4)) = tb[s];
      }
    }
  }
  const char* lBr = diag ? lA : lB;

  // uniform scale from prep's 2048 partials (R11-proven pattern)
  float s_acc = 0.f, q_acc = 0.f;
  #pragma unroll
  for (int t = 0; t < 32; ++t) {
    s_acc += part_s[l + 64*t];
    q_acc += part_q[l + 64*t];
  }
  #pragma unroll
  for (int m = 1; m <= 32; m <<= 1) {
    s_acc += __shfl_xor(s_acc, m);
    q_acc += __shfl_xor(q_acc, m);
  }
  const double n = (double)B_ROWS * FEAT;
  double var = ((double)q_acc - (double)s_acc*(double)s_acc/n) / (n - 1.0);
  float stdv = (float)sqrt(var);
  float p10  = __builtin_amdgcn_exp2f(T[0] * 3.3219280948873623f);
  float nscale2 = -(p10 * 1.4426950408889634f / stdv);

  // per-lane row/col stats
  float sqi[8]; int yiv[8];
  #pragma unroll
  for (int rb = 0; rb < 2; ++rb)
    #pragma unroll
    for (int rr = 0; rr < 4; ++rr) {
      int i = i0 + wr*32 + rb*16 + quad*4 + rr;
      sqi[rb*4+rr] = sq[i]; yiv[rb*4+rr] = y[i];
    }
  float sqj[4]; int yjv[4];
  #pragma unroll
  for (int cb = 0; cb < 4; ++cb) {
    int j = j0 + wc*64 + cb*16 + l15;
    sqj[cb] = sq[j]; yjv[cb] = y[j];
  }

  f32x4 acc[2][4];
  const f32x4 zero4 = {0.f,0.f,0.f,0.f};
  #pragma unroll
  for (int rb = 0; rb < 2; ++rb)
    #pragma unroll
    for (int cb = 0; cb < 4; ++cb) acc[rb][cb] = zero4;

  __syncthreads();   // tiles visible

  #pragma unroll
  for (int kk = 0; kk < 8; ++kk) {
    f16x8 av[2], bv[4];
    #pragma unroll
    for (int rb = 0; rb < 2; ++rb) {
      int m = wr*32 + rb*16 + l15;
      av[rb] = *(const f16x8*)(lA + m*512 + ((((kk<<2)|quad) ^ (l15 & 7)) << 4));
    }
    #pragma unroll
    for (int cb = 0; cb < 4; ++cb) {
      int nr = wc*64 + cb*16 + l15;
      bv[cb] = *(const f16x8*)(lBr + nr*512 + ((((kk<<2)|quad) ^ (l15 & 7)) << 4));
    }
    #pragma unroll
    for (int rb = 0; rb < 2; ++rb)
      #pragma unroll
      for (int cb = 0; cb < 4; ++cb)
        acc[rb][cb] = __builtin_amdgcn_mfma_f32_16x16x32_f16(av[rb], bv[cb], acc[rb][cb], 0, 0, 0);
  }

  // epilogue: e = exp(-dist*scale); row sums (i side) and col sums (j side)
  float rden[8], rnum[8], cden[4], cnum[4];
  #pragma unroll
  for (int v = 0; v < 8; ++v) { rden[v] = 0.f; rnum[v] = 0.f; }
  #pragma unroll
  for (int v = 0; v < 4; ++v) { cden[v] = 0.f; cnum[v] = 0.f; }

  #pragma unroll
  for (int rb = 0; rb < 2; ++rb) {
    #pragma unroll
    for (int rr = 0; rr < 4; ++rr) {
      int ig = i0 + wr*32 + rb*16 + quad*4 + rr;
      float si = sqi[rb*4+rr];
      int   yi = yiv[rb*4+rr];
      #pragma unroll
      for (int cb = 0; cb < 4; ++cb) {
        int jg = j0 + wc*64 + cb*16 + l15;
        float S  = acc[rb][cb][rr];
        float d2 = fmaxf(fmaf(S, -2.0f, si + sqj[cb]), 0.0f);
        float e  = __builtin_amdgcn_exp2f(__builtin_amdgcn_sqrtf(d2) * nscale2);
        if (diag && ig == jg) e = 0.0f;
        bool same = (yi == yjv[cb]);
        rden[rb*4+rr] += e;
        rnum[rb*4+rr] += same ? e : 0.0f;
        cden[cb] += e;
        cnum[cb] += same ? e : 0.0f;
      }
    }
  }

  // row sums: reduce across 16 lanes (j) of each quad
  #pragma unroll
  for (int v = 0; v < 8; ++v) {
    #pragma unroll
    for (int m = 1; m <= 8; m <<= 1) {
      rden[v] += __shfl_xor(rden[v], m);
      rnum[v] += __shfl_xor(rnum[v], m);
    }
  }
  // col sums: reduce across quads (rows)
  #pragma unroll
  for (int v = 0; v < 4; ++v) {
    cden[v] += __shfl_xor(cden[v], 16); cden[v] += __shfl_xor(cden[v], 32);
    cnum[v] += __shfl_xor(cnum[v], 16); cnum[v] += __shfl_xor(cnum[v], 32);
  }

  // block-level reduction in LDS (tile area reusable after barrier)
  __syncthreads();
  float* red = (float*)smem;   // [0:128) rden, [128:256) rnum, [256:384) cden, [384:512) cnum
  red[tid] = 0.f;
  __syncthreads();
  if (l15 == 0) {
    int rbase = wr*32 + quad*4;
    #pragma unroll
    for (int rb = 0; rb < 2; ++rb)
      #pragma unroll
      for (int rr = 0; rr < 4; ++rr) {
        atomicAdd(&red[      rbase + rb*16 + rr], rden[rb*4+rr]);
        atomicAdd(&red[128 + rbase + rb*16 + rr], rnum[rb*4+rr]);
      }
  }
  if (!diag && quad == 0) {
    #pragma unroll
    for (int cb = 0; cb < 4; ++cb) {
      int c = wc*64 + cb*16 + l15;
      atomicAdd(&red[256 + c], cden[cb]);
      atomicAdd(&red[384 + c], cnum[cb]);
    }
  }
  __syncthreads();
  if (tid < 256) {
    int r = tid & 127;
    atomicAdd((tid < 128 ? gden : gnum) + i0 + r, red[tid]);
  } else if (!diag) {
    int r = tid & 127;
    atomicAdd((tid < 384 ? gden : gnum) + j0 + r, red[tid]);
  }
}

// ---- kernel 3: final loss, single 1024-thread block.
// __builtin_amdgcn_logf is LOG2 -> scale by ln(2)  (the R4/5/7/9 bug).
__global__ __launch_bounds__(1024) void final_kernel(
    const float* __restrict__ gden, const float* __restrict__ gnum,
    float* __restrict__ out)
{
  int tid = threadIdx.x;
  float tot = 0.f;
  #pragma unroll
  for (int rr = 0; rr < 8; ++rr) {
    int row = tid + 1024*rr;
    float den = gden[row], num = gnum[row];
    if (num > 0.f)
      tot += 0.6931471805599453f *
             (__builtin_amdgcn_logf(num) - __builtin_amdgcn_logf(den));
  }
  #pragma unroll
  for (int m = 32; m; m >>= 1) tot += __shfl_xor(tot, m);
  __shared__ float red[16];
  if ((tid & 63) == 0) red[tid >> 6] = tot;
  __syncthreads();
  if (tid == 0) {
    float s = 0.f;
    #pragma unroll
    for (int w = 0; w < 16; ++w) s += red[w];
    out[0] = -s / 8192.0f;
  }
}

extern "C" void kernel_launch(void* const* d_in, const int* in_sizes, int n_in,
                              void* d_out, int out_size, void* d_ws, size_t ws_size,
                              hipStream_t stream)
{
  (void)in_sizes; (void)n_in; (void)out_size; (void)ws_size;
  const float* x  = (const float*)d_in[0];
  const int* y    = (const int*)d_in[1];   // int64 in reference -> int32 here
  const float* T  = (const float*)d_in[2];
  char* ws = (char*)d_ws;
  float* part_s = (float*)(ws + 1024);                   // 8 KB
  float* part_q = (float*)(ws + 1024 + 8192);            // 8 KB
  float* sq     = (float*)(ws + 32768);                  // 32 KB
  unsigned short* xh = (unsigned short*)(ws + 65536);    // 4 MB fp16
  float* gden   = (float*)(ws + 65536 + 4194304);        // 32 KB
  float* gnum   = gden + 8192;                           // contiguous with gden

  hipLaunchKernelGGL(prep_kernel, dim3(B_ROWS/4), dim3(256), 0, stream,
                     x, xh, sq, part_s, part_q, gden);
  hipFuncSetAttribute((const void*)snn_main,
                      hipFuncAttributeMaxDynamicSharedMemorySize, 2*TILE_B);
  hipLaunchKernelGGL(snn_main, dim3(NPAIR), dim3(512), 2*TILE_B, stream,
                     xh, sq, y, T, part_s, part_q, gden, gnum);
  hipLaunchKernelGGL(final_kernel, dim3(1), dim3(1024), 0, stream,
                     gden, gnum, (float*)d_out);
}

// Round 14
// 155.260 us; speedup vs baseline: 1.4947x; 1.2481x over previous
//
#include <hip/hip_runtime.h>

#define B_ROWS 8192
#define FEAT   256
#define NPAIR  2080        // 64*65/2 triangular tile pairs
#define TILE_B 65536       // 128 rows x 512 B (256 fp16)

typedef float f32x4 __attribute__((ext_vector_type(4)));
typedef _Float16 f16x8 __attribute__((ext_vector_type(8)));

typedef const __attribute__((address_space(1))) unsigned int* gas_ptr;
typedef __attribute__((address_space(3))) unsigned int* las_ptr;

__device__ __forceinline__ void gload_lds16(const void* g, void* l) {
  // HW semantics: LDS dest = wave-uniform base + lane*16
  __builtin_amdgcn_global_load_lds((gas_ptr)g, (las_ptr)l, 16, 0, 0);
}

// ---- kernel 1: fp16 convert, row ssq, per-block f32 partials;
//      blocks 0..63 also zero gden/gnum (16384 floats, contiguous)
__global__ __launch_bounds__(256) void prep_kernel(
    const float* __restrict__ x, unsigned short* __restrict__ xh,
    float* __restrict__ sq, float* __restrict__ part_s,
    float* __restrict__ part_q, float* __restrict__ gden)
{
  int tid = threadIdx.x;
  int l = tid & 63, wid = tid >> 6;
  int row = blockIdx.x * 4 + wid;
  if (blockIdx.x < 64) gden[blockIdx.x * 256 + tid] = 0.f;
  const float4* xv = (const float4*)(x + (size_t)row * FEAT);
  float4 v = xv[l];
  ushort4 u;
  u.x = __builtin_bit_cast(unsigned short, (_Float16)v.x);
  u.y = __builtin_bit_cast(unsigned short, (_Float16)v.y);
  u.z = __builtin_bit_cast(unsigned short, (_Float16)v.z);
  u.w = __builtin_bit_cast(unsigned short, (_Float16)v.w);
  ((ushort4*)(xh + (size_t)row * FEAT))[l] = u;
  float ssq  = v.x*v.x + v.y*v.y + v.z*v.z + v.w*v.w;
  float ssum = v.x + v.y + v.z + v.w;
  #pragma unroll
  for (int m = 32; m; m >>= 1) {
    ssq  += __shfl_xor(ssq, m);
    ssum += __shfl_xor(ssum, m);
  }
  if (l == 0) sq[row] = ssq;
  __shared__ float red[8];
  if (l == 0) { red[wid*2] = ssum; red[wid*2+1] = ssq; }
  __syncthreads();
  if (tid == 0) {
    part_s[blockIdx.x] = red[0]+red[2]+red[4]+red[6];
    part_q[blockIdx.x] = red[1]+red[3]+red[5]+red[7];
  }
}

// ---- kernel 2: triangular fused Gram + SNN accumulation (R13 body;
// staging switched to swizzle-preserving global_load_lds, no live staging
// VGPRs -> no spill). One block per (ti,tj) pair, tj>=ti; 512 thr = 8 waves.
__global__ __launch_bounds__(512) void snn_main(
    const unsigned short* __restrict__ xh, const float* __restrict__ sq,
    const int* __restrict__ y, const float* __restrict__ T,
    const float* __restrict__ part_s, const float* __restrict__ part_q,
    float* __restrict__ gden, float* __restrict__ gnum)
{
  extern __shared__ char smem[];
  char* lA = smem;
  char* lB = smem + TILE_B;
  int tid = threadIdx.x;
  int l = tid & 63, w = tid >> 6;
  int quad = l >> 4, l15 = l & 15;
  int wr = w >> 1, wc = w & 1;
  int l5 = l >> 5, s31 = l & 31;

  // decode triangular pair index
  int p = blockIdx.x;
  int ti = (int)((129.0 - sqrt(129.0*129.0 - 8.0*(double)p)) * 0.5);
  while ((ti+1)*(129-(ti+1))/2 <= p) ++ti;
  while (ti*(129-ti)/2 > p) --ti;
  int tj = ti + (p - ti*(129-ti)/2);
  bool diag = (ti == tj);
  int i0 = ti*128, j0 = tj*128;

  // stage A (and B if off-diagonal) direct-to-LDS, swizzle-preserving:
  // chunk c = 2 rows = 1024 B; per-lane global granule gg = s31 ^ (rw&7)
  // reproduces the ds_write XOR image exactly (R6/R11-proven pattern).
  const char* xbc = (const char*)xh;
  {
    const char* gA = xbc + (size_t)i0*512;
    #pragma unroll
    for (int s = 0; s < 8; ++s) {
      int c  = w*8 + s;
      int rw = 2*c + l5;
      int gg = s31 ^ (rw & 7);
      gload_lds16(gA + rw*512 + gg*16, lA + c*1024);
    }
    if (!diag) {
      const char* gB = xbc + (size_t)j0*512;
      #pragma unroll
      for (int s = 0; s < 8; ++s) {
        int c  = w*8 + s;
        int rw = 2*c + l5;
        int gg = s31 ^ (rw & 7);
        gload_lds16(gB + rw*512 + gg*16, lB + c*1024);
      }
    }
  }
  const char* lBr = diag ? lA : lB;

  // uniform scale from prep's 2048 partials (latency hidden by DMA drain)
  float s_acc = 0.f, q_acc = 0.f;
  #pragma unroll
  for (int t = 0; t < 32; ++t) {
    s_acc += part_s[l + 64*t];
    q_acc += part_q[l + 64*t];
  }
  #pragma unroll
  for (int m = 1; m <= 32; m <<= 1) {
    s_acc += __shfl_xor(s_acc, m);
    q_acc += __shfl_xor(q_acc, m);
  }
  const double n = (double)B_ROWS * FEAT;
  double var = ((double)q_acc - (double)s_acc*(double)s_acc/n) / (n - 1.0);
  float stdv = (float)sqrt(var);
  float p10  = __builtin_amdgcn_exp2f(T[0] * 3.3219280948873623f);
  float nscale2 = -(p10 * 1.4426950408889634f / stdv);

  // per-lane row/col stats
  float sqi[8]; int yiv[8];
  #pragma unroll
  for (int rb = 0; rb < 2; ++rb)
    #pragma unroll
    for (int rr = 0; rr < 4; ++rr) {
      int i = i0 + wr*32 + rb*16 + quad*4 + rr;
      sqi[rb*4+rr] = sq[i]; yiv[rb*4+rr] = y[i];
    }
  float sqj[4]; int yjv[4];
  #pragma unroll
  for (int cb = 0; cb < 4; ++cb) {
    int j = j0 + wc*64 + cb*16 + l15;
    sqj[cb] = sq[j]; yjv[cb] = y[j];
  }

  f32x4 acc[2][4];
  const f32x4 zero4 = {0.f,0.f,0.f,0.f};
  #pragma unroll
  for (int rb = 0; rb < 2; ++rb)
    #pragma unroll
    for (int cb = 0; cb < 4; ++cb) acc[rb][cb] = zero4;

  __syncthreads();   // drains vmcnt: tiles visible

  #pragma unroll
  for (int kk = 0; kk < 8; ++kk) {
    f16x8 av[2], bv[4];
    #pragma unroll
    for (int rb = 0; rb < 2; ++rb) {
      int m = wr*32 + rb*16 + l15;
      av[rb] = *(const f16x8*)(lA + m*512 + ((((kk<<2)|quad) ^ (l15 & 7)) << 4));
    }
    #pragma unroll
    for (int cb = 0; cb < 4; ++cb) {
      int nr = wc*64 + cb*16 + l15;
      bv[cb] = *(const f16x8*)(lBr + nr*512 + ((((kk<<2)|quad) ^ (l15 & 7)) << 4));
    }
    #pragma unroll
    for (int rb = 0; rb < 2; ++rb)
      #pragma unroll
      for (int cb = 0; cb < 4; ++cb)
        acc[rb][cb] = __builtin_amdgcn_mfma_f32_16x16x32_f16(av[rb], bv[cb], acc[rb][cb], 0, 0, 0);
  }

  // epilogue: e = exp(-dist*scale); row sums (i side) and col sums (j side)
  float rden[8], rnum[8], cden[4], cnum[4];
  #pragma unroll
  for (int v = 0; v < 8; ++v) { rden[v] = 0.f; rnum[v] = 0.f; }
  #pragma unroll
  for (int v = 0; v < 4; ++v) { cden[v] = 0.f; cnum[v] = 0.f; }

  #pragma unroll
  for (int rb = 0; rb < 2; ++rb) {
    #pragma unroll
    for (int rr = 0; rr < 4; ++rr) {
      int ig = i0 + wr*32 + rb*16 + quad*4 + rr;
      float si = sqi[rb*4+rr];
      int   yi = yiv[rb*4+rr];
      #pragma unroll
      for (int cb = 0; cb < 4; ++cb) {
        int jg = j0 + wc*64 + cb*16 + l15;
        float S  = acc[rb][cb][rr];
        float d2 = fmaxf(fmaf(S, -2.0f, si + sqj[cb]), 0.0f);
        float e  = __builtin_amdgcn_exp2f(__builtin_amdgcn_sqrtf(d2) * nscale2);
        if (diag && ig == jg) e = 0.0f;
        bool same = (yi == yjv[cb]);
        rden[rb*4+rr] += e;
        rnum[rb*4+rr] += same ? e : 0.0f;
        cden[cb] += e;
        cnum[cb] += same ? e : 0.0f;
      }
    }
  }

  // row sums: reduce across 16 lanes (j) of each quad
  #pragma unroll
  for (int v = 0; v < 8; ++v) {
    #pragma unroll
    for (int m = 1; m <= 8; m <<= 1) {
      rden[v] += __shfl_xor(rden[v], m);
      rnum[v] += __shfl_xor(rnum[v], m);
    }
  }
  // col sums: reduce across quads (rows)
  #pragma unroll
  for (int v = 0; v < 4; ++v) {
    cden[v] += __shfl_xor(cden[v], 16); cden[v] += __shfl_xor(cden[v], 32);
    cnum[v] += __shfl_xor(cnum[v], 16); cnum[v] += __shfl_xor(cnum[v], 32);
  }

  // block-level reduction in LDS (tile area reusable after barrier)
  __syncthreads();
  float* red = (float*)smem;   // [0:128) rden, [128:256) rnum, [256:384) cden, [384:512) cnum
  red[tid] = 0.f;
  __syncthreads();
  if (l15 == 0) {
    int rbase = wr*32 + quad*4;
    #pragma unroll
    for (int rb = 0; rb < 2; ++rb)
      #pragma unroll
      for (int rr = 0; rr < 4; ++rr) {
        atomicAdd(&red[      rbase + rb*16 + rr], rden[rb*4+rr]);
        atomicAdd(&red[128 + rbase + rb*16 + rr], rnum[rb*4+rr]);
      }
  }
  if (!diag && quad == 0) {
    #pragma unroll
    for (int cb = 0; cb < 4; ++cb) {
      int c = wc*64 + cb*16 + l15;
      atomicAdd(&red[256 + c], cden[cb]);
      atomicAdd(&red[384 + c], cnum[cb]);
    }
  }
  __syncthreads();
  if (tid < 256) {
    int r = tid & 127;
    atomicAdd((tid < 128 ? gden : gnum) + i0 + r, red[tid]);
  } else if (!diag) {
    int r = tid & 127;
    atomicAdd((tid < 384 ? gden : gnum) + j0 + r, red[tid]);
  }
}

// ---- kernel 3: final loss, single 1024-thread block.
// __builtin_amdgcn_logf is LOG2 -> scale by ln(2)  (the R4/5/7/9 bug).
__global__ __launch_bounds__(1024) void final_kernel(
    const float* __restrict__ gden, const float* __restrict__ gnum,
    float* __restrict__ out)
{
  int tid = threadIdx.x;
  float tot = 0.f;
  #pragma unroll
  for (int rr = 0; rr < 8; ++rr) {
    int row = tid + 1024*rr;
    float den = gden[row], num = gnum[row];
    if (num > 0.f)
      tot += 0.6931471805599453f *
             (__builtin_amdgcn_logf(num) - __builtin_amdgcn_logf(den));
  }
  #pragma unroll
  for (int m = 32; m; m >>= 1) tot += __shfl_xor(tot, m);
  __shared__ float red[16];
  if ((tid & 63) == 0) red[tid >> 6] = tot;
  __syncthreads();
  if (tid == 0) {
    float s = 0.f;
    #pragma unroll
    for (int w = 0; w < 16; ++w) s += red[w];
    out[0] = -s / 8192.0f;
  }
}

extern "C" void kernel_launch(void* const* d_in, const int* in_sizes, int n_in,
                              void* d_out, int out_size, void* d_ws, size_t ws_size,
                              hipStream_t stream)
{
  (void)in_sizes; (void)n_in; (void)out_size; (void)ws_size;
  const float* x  = (const float*)d_in[0];
  const int* y    = (const int*)d_in[1];   // int64 in reference -> int32 here
  const float* T  = (const float*)d_in[2];
  char* ws = (char*)d_ws;
  float* part_s = (float*)(ws + 1024);                   // 8 KB
  float* part_q = (float*)(ws + 1024 + 8192);            // 8 KB
  float* sq     = (float*)(ws + 32768);                  // 32 KB
  unsigned short* xh = (unsigned short*)(ws + 65536);    // 4 MB fp16
  float* gden   = (float*)(ws + 65536 + 4194304);        // 32 KB
  float* gnum   = gden + 8192;                           // contiguous with gden

  hipLaunchKernelGGL(prep_kernel, dim3(B_ROWS/4), dim3(256), 0, stream,
                     x, xh, sq, part_s, part_q, gden);
  hipFuncSetAttribute((const void*)snn_main,
                      hipFuncAttributeMaxDynamicSharedMemorySize, 2*TILE_B);
  hipLaunchKernelGGL(snn_main, dim3(NPAIR), dim3(512), 2*TILE_B, stream,
                     xh, sq, y, T, part_s, part_q, gden, gnum);
  hipLaunchKernelGGL(final_kernel, dim3(1), dim3(1024), 0, stream,
                     gden, gnum, (float*)d_out);
}

// Round 15
// 139.242 us; speedup vs baseline: 1.6667x; 1.1150x over previous
//
#include <hip/hip_runtime.h>

#define B_ROWS 8192
#define FEAT   256
#define NPAIR  4160        // sum_{it<64} (128-2*it): triangular (it, jt64) pairs

typedef float f32x4 __attribute__((ext_vector_type(4)));
typedef _Float16 f16x8 __attribute__((ext_vector_type(8)));

typedef const __attribute__((address_space(1))) unsigned int* gas_ptr;
typedef __attribute__((address_space(3))) unsigned int* las_ptr;

__device__ __forceinline__ void gload_lds16(const void* g, void* l) {
  // HW semantics: LDS dest = wave-uniform base + lane*16
  __builtin_amdgcn_global_load_lds((gas_ptr)g, (las_ptr)l, 16, 0, 0);
}

// ---- kernel 1: fp16 convert, row ssq, per-block f32 partials;
//      blocks 0..63 also zero gden/gnum (16384 floats, contiguous)
__global__ __launch_bounds__(256) void prep_kernel(
    const float* __restrict__ x, unsigned short* __restrict__ xh,
    float* __restrict__ sq, float* __restrict__ part_s,
    float* __restrict__ part_q, float* __restrict__ gden)
{
  int tid = threadIdx.x;
  int l = tid & 63, wid = tid >> 6;
  int row = blockIdx.x * 4 + wid;
  if (blockIdx.x < 64) gden[blockIdx.x * 256 + tid] = 0.f;
  const float4* xv = (const float4*)(x + (size_t)row * FEAT);
  float4 v = xv[l];
  ushort4 u;
  u.x = __builtin_bit_cast(unsigned short, (_Float16)v.x);
  u.y = __builtin_bit_cast(unsigned short, (_Float16)v.y);
  u.z = __builtin_bit_cast(unsigned short, (_Float16)v.z);
  u.w = __builtin_bit_cast(unsigned short, (_Float16)v.w);
  ((ushort4*)(xh + (size_t)row * FEAT))[l] = u;
  float ssq  = v.x*v.x + v.y*v.y + v.z*v.z + v.w*v.w;
  float ssum = v.x + v.y + v.z + v.w;
  #pragma unroll
  for (int m = 32; m; m >>= 1) {
    ssq  += __shfl_xor(ssq, m);
    ssum += __shfl_xor(ssum, m);
  }
  if (l == 0) sq[row] = ssq;
  __shared__ float red[8];
  if (l == 0) { red[wid*2] = ssum; red[wid*2+1] = ssq; }
  __syncthreads();
  if (tid == 0) {
    part_s[blockIdx.x] = red[0]+red[2]+red[4]+red[6];
    part_q[blockIdx.x] = red[1]+red[3]+red[5]+red[7];
  }
}

// ---- kernel 2: triangular Gram+SNN on the R11 chassis.
// One block per (it, jt) pair, jt >= 2*it; tile = 128 rows x 64 cols.
// 256 thr = 4 waves of 32x64; A fragments register-resident (R11-proven
// layout); LDS = 32 KB B tile; launch_bounds(256,2) -> 2 blocks/CU.
// Boundary tiles (jt-2it < 2) mask to strictly-upper (j > i); every tile
// adds row sums (i side) AND col sums (j side) -> each unordered pair
// counted exactly once, both endpoints credited.
__global__ __launch_bounds__(256, 2) void snn_main(
    const unsigned short* __restrict__ xh, const float* __restrict__ sq,
    const int* __restrict__ y, const float* __restrict__ T,
    const float* __restrict__ part_s, const float* __restrict__ part_q,
    float* __restrict__ gden, float* __restrict__ gnum)
{
  __shared__ __align__(16) char lB[32768];
  __shared__ float red[384];
  int tid = threadIdx.x;
  int l = tid & 63, wid = tid >> 6;     // wid = row strip (0..3)
  int quad = l >> 4, l15 = l & 15;
  int l5 = l >> 5, s31 = l & 31;

  // decode triangular pair: S(it) = it*(129-it), jt = 2it + (p - S(it))
  int p = blockIdx.x;
  int it = (int)((129.0 - sqrt(129.0*129.0 - 4.0*(double)p)) * 0.5);
  while ((it+1)*(129-(it+1)) <= p) ++it;
  while (it*(129-it) > p) --it;
  int rem = p - it*(129-it);
  int jt = 2*it + rem;
  bool dg = (rem < 2);                  // tile straddles the diagonal
  int i0 = it*128, j0 = jt*64;

  const char* xbc = (const char*)xh;

  // stage B tile (rows j0..j0+64) direct-to-LDS, swizzle-preserving
  {
    const char* gB = xbc + (size_t)j0 * 512;
    #pragma unroll
    for (int s = 0; s < 8; ++s) {
      int c  = wid*8 + s;
      int rw = 2*c + l5;
      int gg = s31 ^ (rw & 7);
      gload_lds16(gB + rw*512 + gg*16, lB + c*1024);
    }
  }

  // A fragments -> registers (R11-proven MFMA A layout)
  f16x8 areg[2][8];
  #pragma unroll
  for (int rb = 0; rb < 2; ++rb)
    #pragma unroll
    for (int kk = 0; kk < 8; ++kk)
      areg[rb][kk] = *(const f16x8*)(xbc +
          (size_t)(i0 + wid*32 + rb*16 + l15)*512 + kk*64 + quad*16);

  // uniform scale from prep's 2048 partials (hidden behind DMA drain)
  float s_acc = 0.f, q_acc = 0.f;
  #pragma unroll
  for (int t = 0; t < 32; ++t) {
    s_acc += part_s[l + 64*t];
    q_acc += part_q[l + 64*t];
  }
  #pragma unroll
  for (int m = 1; m <= 32; m <<= 1) {
    s_acc += __shfl_xor(s_acc, m);
    q_acc += __shfl_xor(q_acc, m);
  }
  const double n = (double)B_ROWS * FEAT;
  double var = ((double)q_acc - (double)s_acc*(double)s_acc/n) / (n - 1.0);
  float stdv = (float)sqrt(var);
  float p10  = __builtin_amdgcn_exp2f(T[0] * 3.3219280948873623f);
  float nscale2 = -(p10 * 1.4426950408889634f / stdv);

  // per-lane row/col stats
  float sqi[8]; int yiv[8];
  int i0q = i0 + wid*32 + quad*4;
  #pragma unroll
  for (int rb = 0; rb < 2; ++rb)
    #pragma unroll
    for (int rr = 0; rr < 4; ++rr) {
      int i = i0q + rb*16 + rr;
      sqi[rb*4+rr] = sq[i]; yiv[rb*4+rr] = y[i];
    }
  float sqj[4]; int yjv[4];
  #pragma unroll
  for (int cb = 0; cb < 4; ++cb) {
    int j = j0 + cb*16 + l15;
    sqj[cb] = sq[j]; yjv[cb] = y[j];
  }

  f32x4 acc[2][4];
  const f32x4 zero4 = {0.f,0.f,0.f,0.f};
  #pragma unroll
  for (int rb = 0; rb < 2; ++rb)
    #pragma unroll
    for (int cb = 0; cb < 4; ++cb) acc[rb][cb] = zero4;

  __syncthreads();   // drains vmcnt: B tile visible

  #pragma unroll
  for (int kk = 0; kk < 8; ++kk) {
    f16x8 bv[4];
    #pragma unroll
    for (int cb = 0; cb < 4; ++cb) {
      int nr = cb*16 + l15;
      bv[cb] = *(const f16x8*)(lB + nr*512 + ((((kk<<2)|quad) ^ (l15 & 7)) << 4));
    }
    #pragma unroll
    for (int rb = 0; rb < 2; ++rb)
      #pragma unroll
      for (int cb = 0; cb < 4; ++cb)
        acc[rb][cb] = __builtin_amdgcn_mfma_f32_16x16x32_f16(
            areg[rb][kk], bv[cb], acc[rb][cb], 0, 0, 0);
  }

  // epilogue: row sums (i side) + col sums (j side); boundary mask j>i
  float rden[8], rnum[8], cden[4], cnum[4];
  #pragma unroll
  for (int v = 0; v < 8; ++v) { rden[v] = 0.f; rnum[v] = 0.f; }
  #pragma unroll
  for (int v = 0; v < 4; ++v) { cden[v] = 0.f; cnum[v] = 0.f; }

  #pragma unroll
  for (int rb = 0; rb < 2; ++rb) {
    #pragma unroll
    for (int rr = 0; rr < 4; ++rr) {
      int ig = i0q + rb*16 + rr;
      float si = sqi[rb*4+rr];
      int   yi = yiv[rb*4+rr];
      #pragma unroll
      for (int cb = 0; cb < 4; ++cb) {
        int jg = j0 + cb*16 + l15;
        float S  = acc[rb][cb][rr];
        float d2 = fmaxf(fmaf(S, -2.0f, si + sqj[cb]), 0.0f);
        float e  = __builtin_amdgcn_exp2f(__builtin_amdgcn_sqrtf(d2) * nscale2);
        if (dg && jg <= ig) e = 0.0f;      // strictly-upper only
        bool same = (yi == yjv[cb]);
        rden[rb*4+rr] += e;
        rnum[rb*4+rr] += same ? e : 0.0f;
        cden[cb] += e;
        cnum[cb] += same ? e : 0.0f;
      }
    }
  }

  // row sums: reduce across the 16 lanes (j) of each quad
  #pragma unroll
  for (int v = 0; v < 8; ++v) {
    #pragma unroll
    for (int m = 1; m <= 8; m <<= 1) {
      rden[v] += __shfl_xor(rden[v], m);
      rnum[v] += __shfl_xor(rnum[v], m);
    }
  }
  // col sums: reduce across quads (rows within the wave)
  #pragma unroll
  for (int v = 0; v < 4; ++v) {
    cden[v] += __shfl_xor(cden[v], 16); cden[v] += __shfl_xor(cden[v], 32);
    cnum[v] += __shfl_xor(cnum[v], 16); cnum[v] += __shfl_xor(cnum[v], 32);
  }

  // block-level reduction (R14-proven pattern), then global atomic flush
  __syncthreads();
  for (int b = tid; b < 384; b += 256) red[b] = 0.f;
  __syncthreads();
  if (l15 == 0) {
    int rbase = wid*32 + quad*4;
    #pragma unroll
    for (int rb = 0; rb < 2; ++rb)
      #pragma unroll
      for (int rr = 0; rr < 4; ++rr) {
        atomicAdd(&red[      rbase + rb*16 + rr], rden[rb*4+rr]);
        atomicAdd(&red[128 + rbase + rb*16 + rr], rnum[rb*4+rr]);
      }
  }
  if (quad == 0) {
    #pragma unroll
    for (int cb = 0; cb < 4; ++cb) {
      int c = cb*16 + l15;
      atomicAdd(&red[256 + c], cden[cb]);
      atomicAdd(&red[320 + c], cnum[cb]);
    }
  }
  __syncthreads();
  for (int b = tid; b < 384; b += 256) {
    float v = red[b];
    if      (b < 128) atomicAdd(&gden[i0 + b],       v);
    else if (b < 256) atomicAdd(&gnum[i0 + b - 128], v);
    else if (b < 320) atomicAdd(&gden[j0 + b - 256], v);
    else              atomicAdd(&gnum[j0 + b - 320], v);
  }
}

// ---- kernel 3: final loss, single 1024-thread block.
// __builtin_amdgcn_logf is LOG2 -> scale by ln(2)  (the R4/5/7/9 bug).
__global__ __launch_bounds__(1024) void final_kernel(
    const float* __restrict__ gden, const float* __restrict__ gnum,
    float* __restrict__ out)
{
  int tid = threadIdx.x;
  float tot = 0.f;
  #pragma unroll
  for (int rr = 0; rr < 8; ++rr) {
    int row = tid + 1024*rr;
    float den = gden[row], num = gnum[row];
    if (num > 0.f)
      tot += 0.6931471805599453f *
             (__builtin_amdgcn_logf(num) - __builtin_amdgcn_logf(den));
  }
  #pragma unroll
  for (int m = 32; m; m >>= 1) tot += __shfl_xor(tot, m);
  __shared__ float red[16];
  if ((tid & 63) == 0) red[tid >> 6] = tot;
  __syncthreads();
  if (tid == 0) {
    float s = 0.f;
    #pragma unroll
    for (int w = 0; w < 16; ++w) s += red[w];
    out[0] = -s / 8192.0f;
  }
}

extern "C" void kernel_launch(void* const* d_in, const int* in_sizes, int n_in,
                              void* d_out, int out_size, void* d_ws, size_t ws_size,
                              hipStream_t stream)
{
  (void)in_sizes; (void)n_in; (void)out_size; (void)ws_size;
  const float* x  = (const float*)d_in[0];
  const int* y    = (const int*)d_in[1];   // int64 in reference -> int32 here
  const float* T  = (const float*)d_in[2];
  char* ws = (char*)d_ws;
  float* part_s = (float*)(ws + 1024);                   // 8 KB
  float* part_q = (float*)(ws + 1024 + 8192);            // 8 KB
  float* sq     = (float*)(ws + 32768);                  // 32 KB
  unsigned short* xh = (unsigned short*)(ws + 65536);    // 4 MB fp16
  float* gden   = (float*)(ws + 65536 + 4194304);        // 32 KB
  float* gnum   = gden + 8192;                           // contiguous with gden

  hipLaunchKernelGGL(prep_kernel, dim3(B_ROWS/4), dim3(256), 0, stream,
                     x, xh, sq, part_s, part_q, gden);
  hipLaunchKernelGGL(snn_main, dim3(NPAIR), dim3(256), 0, stream,
                     xh, sq, y, T, part_s, part_q, gden, gnum);
  hipLaunchKernelGGL(final_kernel, dim3(1), dim3(1024), 0, stream,
                     gden, gnum, (float*)d_out);
}

// Round 16
// 122.514 us; speedup vs baseline: 1.8943x; 1.1365x over previous
//
#include <hip/hip_runtime.h>

#define B_ROWS 8192
#define FEAT   256
#define NBLK   1056        // sum_{it<64} ceil((128-2it)/4) = 32*33

typedef float f32x4 __attribute__((ext_vector_type(4)));
typedef _Float16 f16x8 __attribute__((ext_vector_type(8)));

typedef const __attribute__((address_space(1))) unsigned int* gas_ptr;
typedef __attribute__((address_space(3))) unsigned int* las_ptr;

__device__ __forceinline__ void gload_lds16(const void* g, void* l) {
  __builtin_amdgcn_global_load_lds((gas_ptr)g, (las_ptr)l, 16, 0, 0);
}

// prefix: #blocks for row-tiles < it   (chunk = 4 j-tiles)
__device__ __forceinline__ int pfx(int it) {
  int m = it >> 1;
  return m*(65 - m) + ((it & 1) ? (32 - m) : 0);
}

// ---- kernel 1: fp16 convert, row ssq, per-block f32 partials;
//      blocks 0..63 also zero gden/gnum (16384 floats, contiguous)
__global__ __launch_bounds__(256) void prep_kernel(
    const float* __restrict__ x, unsigned short* __restrict__ xh,
    float* __restrict__ sq, float* __restrict__ part_s,
    float* __restrict__ part_q, float* __restrict__ gden)
{
  int tid = threadIdx.x;
  int l = tid & 63, wid = tid >> 6;
  int row = blockIdx.x * 4 + wid;
  if (blockIdx.x < 64) gden[blockIdx.x * 256 + tid] = 0.f;
  const float4* xv = (const float4*)(x + (size_t)row * FEAT);
  float4 v = xv[l];
  ushort4 u;
  u.x = __builtin_bit_cast(unsigned short, (_Float16)v.x);
  u.y = __builtin_bit_cast(unsigned short, (_Float16)v.y);
  u.z = __builtin_bit_cast(unsigned short, (_Float16)v.z);
  u.w = __builtin_bit_cast(unsigned short, (_Float16)v.w);
  ((ushort4*)(xh + (size_t)row * FEAT))[l] = u;
  float ssq  = v.x*v.x + v.y*v.y + v.z*v.z + v.w*v.w;
  float ssum = v.x + v.y + v.z + v.w;
  #pragma unroll
  for (int m = 32; m; m >>= 1) {
    ssq  += __shfl_xor(ssq, m);
    ssum += __shfl_xor(ssum, m);
  }
  if (l == 0) sq[row] = ssq;
  __shared__ float red[8];
  if (l == 0) { red[wid*2] = ssum; red[wid*2+1] = ssq; }
  __syncthreads();
  if (tid == 0) {
    part_s[blockIdx.x] = red[0]+red[2]+red[4]+red[6];
    part_q[blockIdx.x] = red[1]+red[3]+red[5]+red[7];
  }
}

// ---- kernel 2: triangular Gram+SNN, multi-step blocks (R11 loop + R15
// triangle). Block = (it, chunk c of 4 j-tiles), jt = 2it+4c+s. 256 thr =
// 4 waves of 32(i) x 64(j); areg resident; LDS = 32 KB B tile; 2 blocks/CU.
__global__ __launch_bounds__(256, 2) void snn_main(
    const unsigned short* __restrict__ xh, const float* __restrict__ sq,
    const int* __restrict__ y, const float* __restrict__ T,
    const float* __restrict__ part_s, const float* __restrict__ part_q,
    float* __restrict__ gden, float* __restrict__ gnum)
{
  __shared__ __align__(16) char lB[32768];
  int tid = threadIdx.x;
  int l = tid & 63, wid = tid >> 6;     // wid = row strip (0..3)
  int quad = l >> 4, l15 = l & 15;
  int l5 = l >> 5, s31 = l & 31;

  // decode p -> (it, c)
  int p = blockIdx.x;
  int m = (int)((65.0 - sqrt(65.0*65.0 - 4.0*(double)p)) * 0.5);
  if (m < 0) m = 0; if (m > 32) m = 32;
  int it = 2*m; if (it > 63) it = 63;
  while (it < 63 && pfx(it+1) <= p) ++it;
  while (it > 0 && pfx(it) > p) --it;
  int c   = p - pfx(it);
  int jt0 = 2*it + 4*c;
  int steps = 128 - jt0; if (steps > 4) steps = 4;
  int i0 = it*128;

  const char* xbc = (const char*)xh;

  // A fragments -> registers (R11-proven MFMA A layout)
  f16x8 areg[2][8];
  #pragma unroll
  for (int rb = 0; rb < 2; ++rb)
    #pragma unroll
    for (int kk = 0; kk < 8; ++kk)
      areg[rb][kk] = *(const f16x8*)(xbc +
          (size_t)(i0 + wid*32 + rb*16 + l15)*512 + kk*64 + quad*16);

  // uniform scale from prep's 2048 partials
  float s_acc = 0.f, q_acc = 0.f;
  #pragma unroll
  for (int t = 0; t < 32; ++t) {
    s_acc += part_s[l + 64*t];
    q_acc += part_q[l + 64*t];
  }
  #pragma unroll
  for (int mm = 1; mm <= 32; mm <<= 1) {
    s_acc += __shfl_xor(s_acc, mm);
    q_acc += __shfl_xor(q_acc, mm);
  }
  const double n = (double)B_ROWS * FEAT;
  double var = ((double)q_acc - (double)s_acc*(double)s_acc/n) / (n - 1.0);
  float stdv = (float)sqrt(var);
  float p10  = __builtin_amdgcn_exp2f(T[0] * 3.3219280948873623f);
  float nscale2 = -(p10 * 1.4426950408889634f / stdv);

  // per-lane row stats
  float sqi[8]; int yiv[8];
  int i0q = i0 + wid*32 + quad*4;
  #pragma unroll
  for (int rb = 0; rb < 2; ++rb)
    #pragma unroll
    for (int rr = 0; rr < 4; ++rr) {
      int i = i0q + rb*16 + rr;
      sqi[rb*4+rr] = sq[i]; yiv[rb*4+rr] = y[i];
    }

  float rden[8], rnum[8];
  #pragma unroll
  for (int v = 0; v < 8; ++v) { rden[v] = 0.f; rnum[v] = 0.f; }
  f32x4 acc[2][4];
  const f32x4 zero4 = {0.f,0.f,0.f,0.f};

  // epilogue for one completed step (j-tile at jp0), col flush inside
  auto do_epilogue = [&](int jp0, bool dg) {
    float sqj[4]; int yjv[4];
    #pragma unroll
    for (int cb = 0; cb < 4; ++cb) {
      int j = jp0 + cb*16 + l15;
      sqj[cb] = sq[j]; yjv[cb] = y[j];
    }
    float cden[4], cnum[4];
    #pragma unroll
    for (int v = 0; v < 4; ++v) { cden[v] = 0.f; cnum[v] = 0.f; }
    #pragma unroll
    for (int rb = 0; rb < 2; ++rb) {
      #pragma unroll
      for (int rr = 0; rr < 4; ++rr) {
        int ig = i0q + rb*16 + rr;
        float si = sqi[rb*4+rr];
        int   yi = yiv[rb*4+rr];
        #pragma unroll
        for (int cb = 0; cb < 4; ++cb) {
          int jg = jp0 + cb*16 + l15;
          float S  = acc[rb][cb][rr];
          float d2 = fmaxf(fmaf(S, -2.0f, si + sqj[cb]), 0.0f);
          float e  = __builtin_amdgcn_exp2f(__builtin_amdgcn_sqrtf(d2) * nscale2);
          if (dg && jg <= ig) e = 0.0f;
          bool same = (yi == yjv[cb]);
          rden[rb*4+rr] += e;
          rnum[rb*4+rr] += same ? e : 0.0f;
          cden[cb] += e;
          cnum[cb] += same ? e : 0.0f;
        }
      }
    }
    // col sums: reduce across quads (32 rows of this wave), flush to global
    #pragma unroll
    for (int v = 0; v < 4; ++v) {
      cden[v] += __shfl_xor(cden[v], 16); cden[v] += __shfl_xor(cden[v], 32);
      cnum[v] += __shfl_xor(cnum[v], 16); cnum[v] += __shfl_xor(cnum[v], 32);
    }
    if (quad == 0) {
      #pragma unroll
      for (int cb = 0; cb < 4; ++cb) {
        int j = jp0 + cb*16 + l15;
        atomicAdd(&gden[j], cden[cb]);
        atomicAdd(&gnum[j], cnum[cb]);
      }
    }
  };

  for (int s = 0; s < steps; ++s) {
    int j0 = (jt0 + s) * 64;

    __syncthreads();   // all waves done reading lB of previous step
    {
      const char* gB = xbc + (size_t)j0 * 512;
      #pragma unroll
      for (int ss = 0; ss < 8; ++ss) {
        int cc = wid*8 + ss;
        int rw = 2*cc + l5;
        int gg = s31 ^ (rw & 7);
        gload_lds16(gB + rw*512 + gg*16, lB + cc*1024);
      }
    }

    if (s > 0) do_epilogue(j0 - 64, (c == 0 && s - 1 < 2));

    #pragma unroll
    for (int rb = 0; rb < 2; ++rb)
      #pragma unroll
      for (int cb = 0; cb < 4; ++cb)
        acc[rb][cb] = zero4;

    __syncthreads();   // drains vmcnt: B tile visible

    #pragma unroll
    for (int kk = 0; kk < 8; ++kk) {
      f16x8 bv[4];
      #pragma unroll
      for (int cb = 0; cb < 4; ++cb) {
        int nr = cb*16 + l15;
        bv[cb] = *(const f16x8*)(lB + nr*512 + ((((kk<<2)|quad) ^ (l15 & 7)) << 4));
      }
      #pragma unroll
      for (int rb = 0; rb < 2; ++rb)
        #pragma unroll
        for (int cb = 0; cb < 4; ++cb)
          acc[rb][cb] = __builtin_amdgcn_mfma_f32_16x16x32_f16(
              areg[rb][kk], bv[cb], acc[rb][cb], 0, 0, 0);
    }
  }
  do_epilogue((jt0 + steps - 1) * 64, (c == 0 && steps - 1 < 2));

  // row sums: reduce across the 16 lanes of each quad, flush to global
  #pragma unroll
  for (int v = 0; v < 8; ++v) {
    #pragma unroll
    for (int mm = 1; mm <= 8; mm <<= 1) {
      rden[v] += __shfl_xor(rden[v], mm);
      rnum[v] += __shfl_xor(rnum[v], mm);
    }
  }
  if (l15 == 0) {
    #pragma unroll
    for (int rb = 0; rb < 2; ++rb)
      #pragma unroll
      for (int rr = 0; rr < 4; ++rr) {
        int i = i0q + rb*16 + rr;
        atomicAdd(&gden[i], rden[rb*4+rr]);
        atomicAdd(&gnum[i], rnum[rb*4+rr]);
      }
  }
}

// ---- kernel 3: final loss, single 1024-thread block.
// __builtin_amdgcn_logf is LOG2 -> scale by ln(2)  (the R4/5/7/9 bug).
__global__ __launch_bounds__(1024) void final_kernel(
    const float* __restrict__ gden, const float* __restrict__ gnum,
    float* __restrict__ out)
{
  int tid = threadIdx.x;
  float tot = 0.f;
  #pragma unroll
  for (int rr = 0; rr < 8; ++rr) {
    int row = tid + 1024*rr;
    float den = gden[row], num = gnum[row];
    if (num > 0.f)
      tot += 0.6931471805599453f *
             (__builtin_amdgcn_logf(num) - __builtin_amdgcn_logf(den));
  }
  #pragma unroll
  for (int m = 32; m; m >>= 1) tot += __shfl_xor(tot, m);
  __shared__ float red[16];
  if ((tid & 63) == 0) red[tid >> 6] = tot;
  __syncthreads();
  if (tid == 0) {
    float s = 0.f;
    #pragma unroll
    for (int w = 0; w < 16; ++w) s += red[w];
    out[0] = -s / 8192.0f;
  }
}

extern "C" void kernel_launch(void* const* d_in, const int* in_sizes, int n_in,
                              void* d_out, int out_size, void* d_ws, size_t ws_size,
                              hipStream_t stream)
{
  (void)in_sizes; (void)n_in; (void)out_size; (void)ws_size;
  const float* x  = (const float*)d_in[0];
  const int* y    = (const int*)d_in[1];   // int64 in reference -> int32 here
  const float* T  = (const float*)d_in[2];
  char* ws = (char*)d_ws;
  float* part_s = (float*)(ws + 1024);                   // 8 KB
  float* part_q = (float*)(ws + 1024 + 8192);            // 8 KB
  float* sq     = (float*)(ws + 32768);                  // 32 KB
  unsigned short* xh = (unsigned short*)(ws + 65536);    // 4 MB fp16
  float* gden   = (float*)(ws + 65536 + 4194304);        // 32 KB
  float* gnum   = gden + 8192;                           // contiguous with gden

  hipLaunchKernelGGL(prep_kernel, dim3(B_ROWS/4), dim3(256), 0, stream,
                     x, xh, sq, part_s, part_q, gden);
  hipLaunchKernelGGL(snn_main, dim3(NBLK), dim3(256), 0, stream,
                     xh, sq, y, T, part_s, part_q, gden, gnum);
  hipLaunchKernelGGL(final_kernel, dim3(1), dim3(1024), 0, stream,
                     gden, gnum, (float*)d_out);
}